// Round 1
// baseline (231.196 us; speedup 1.0000x reference)
//
#include <hip/hip_runtime.h>

// LIF recurrence: mem = tau*mem + x[t]; spike = (mem > v_th); mem *= (1-spike)
// Shapes: x [T,B,C,H,W] fp32, mem0 [1,C,H,W] fp32, out spikes [T,B,C,H,W] fp32.
// T=4, B=64, C=128, H=W=32. Memory-bound elementwise scan: ~268 MB HBM traffic.

#ifndef LIF_T
#define LIF_T 4
#endif

__global__ __launch_bounds__(256) void
lif_kernel(const float4* __restrict__ x,     // [T, N4] float4 view
           const float4* __restrict__ mem0,  // [CHW4] float4 view (broadcast over B)
           float4* __restrict__ out,         // [T, N4]
           int n4, int chw4_mask) {
    int i = blockIdx.x * blockDim.x + threadIdx.x;
    if (i >= n4) return;

    const float TAU = 0.25f;
    const float V_TH = 1.0f;

    float4 mem = mem0[i & chw4_mask];

#pragma unroll
    for (int t = 0; t < LIF_T; ++t) {
        float4 xt = x[(size_t)t * n4 + i];
        float4 s;

        mem.x = TAU * mem.x + xt.x;
        mem.y = TAU * mem.y + xt.y;
        mem.z = TAU * mem.z + xt.z;
        mem.w = TAU * mem.w + xt.w;

        s.x = (mem.x > V_TH) ? 1.0f : 0.0f;
        s.y = (mem.y > V_TH) ? 1.0f : 0.0f;
        s.z = (mem.z > V_TH) ? 1.0f : 0.0f;
        s.w = (mem.w > V_TH) ? 1.0f : 0.0f;

        // reset: mem *= (1 - spike)  ==  select 0 where spiked
        mem.x = (mem.x > V_TH) ? 0.0f : mem.x;
        mem.y = (mem.y > V_TH) ? 0.0f : mem.y;
        mem.z = (mem.z > V_TH) ? 0.0f : mem.z;
        mem.w = (mem.w > V_TH) ? 0.0f : mem.w;

        out[(size_t)t * n4 + i] = s;
    }
}

extern "C" void kernel_launch(void* const* d_in, const int* in_sizes, int n_in,
                              void* d_out, int out_size, void* d_ws, size_t ws_size,
                              hipStream_t stream) {
    const float* x    = (const float*)d_in[0];   // [T,B,C,H,W]
    const float* mem0 = (const float*)d_in[1];   // [1,C,H,W]
    float* out        = (float*)d_out;           // [T,B,C,H,W]

    const int T = LIF_T;
    const int total = in_sizes[0];        // T*B*C*H*W
    const int bchw  = total / T;          // per-timestep elements
    const int n4    = bchw / 4;           // float4 count per timestep
    const int chw4  = in_sizes[1] / 4;    // mem0 float4 count (power of 2)

    const int block = 256;
    const int grid  = (n4 + block - 1) / block;

    lif_kernel<<<grid, block, 0, stream>>>(
        (const float4*)x, (const float4*)mem0, (float4*)out,
        n4, chw4 - 1);
}